// Round 15
// baseline (372.254 us; speedup 1.0000x reference)
//
#include <hip/hip_runtime.h>
#include <stdint.h>

typedef __attribute__((ext_vector_type(8))) short short8;
typedef __attribute__((ext_vector_type(4))) float f32x4;

// HW packed f32->bf16 (RNE): dst.lo = bf16(a), dst.hi = bf16(b). gfx950.
__device__ __forceinline__ uint32_t pk2bf(float a, float b) {
  uint32_t r;
  asm("v_cvt_pk_bf16_f32 %0, %1, %2" : "=v"(r) : "v"(a), "v"(b));
  return r;
}
__device__ __forceinline__ uint16_t f2bf(float a) {
  uint32_t ua = __builtin_bit_cast(uint32_t, a);
  return (uint16_t)((ua + 0x7FFFu + ((ua >> 16) & 1u)) >> 16);
}
__device__ __forceinline__ float bflo(uint32_t w) { return __builtin_bit_cast(float, w << 16); }
__device__ __forceinline__ float bfhi(uint32_t w) { return __builtin_bit_cast(float, w & 0xFFFF0000u); }

__device__ __forceinline__ void gload_lds16(const void* g, void* l) {
  __builtin_amdgcn_global_load_lds(
      (const __attribute__((address_space(1))) uint32_t*)g,
      (__attribute__((address_space(3))) uint32_t*)l, 16, 0, 0);
}

// ---------------------------------------------------------------------------
// K0: convert Wq/Wk/Wv (512x512 f32 each) to bf16, contiguous Wb[3][262144].
// ---------------------------------------------------------------------------
__global__ __launch_bounds__(256) void k_cvtw(const float* __restrict__ Wq,
                                              const float* __restrict__ Wk,
                                              const float* __restrict__ Wv,
                                              uint16_t* __restrict__ Wb) {
  const int idx = blockIdx.x * 256 + threadIdx.x;
  const int sel = idx >> 16;
  const int e = idx & 65535;
  const float* src = (sel == 0) ? Wq : (sel == 1) ? Wk : Wv;
  const float4 v = *(const float4*)(src + (size_t)e * 4);
  uint2 p;
  p.x = pk2bf(v.x, v.y);
  p.y = pk2bf(v.z, v.w);
  *(uint2*)(Wb + (size_t)sel * 262144 + (size_t)e * 4) = p;
}

// ---------------------------------------------------------------------------
// K1: QKV projection GEMM — DEPTH-2 derived-wait pipeline, NOW WITH
// sched_barrier(0) fences (raw s_barrier is NOT a compiler memory fence;
// r14's missing fences let the stage DMA cross the barrier -> race -> NaN).
// Tile 128x256, BK=64, 512 thr (8 waves 2x4, wave tile 64x64), dbuf 129KB.
// Per iter t: vmcnt(8) -> bar -> ds_read all frags(t) -> lgkmcnt(0) -> bar
//             -> stage(buf[t&1], t+2) -> cvt+MFMA (setprio).
// ---------------------------------------------------------------------------
__global__ __launch_bounds__(512, 2) void k_gemm_qkv(
    const float* __restrict__ qin, const float* __restrict__ sin_,
    const uint16_t* __restrict__ Wb,
    const float* __restrict__ bq, const float* __restrict__ bk,
    const float* __restrict__ bv,
    uint16_t* __restrict__ Qb, uint16_t* __restrict__ Kb, uint16_t* __restrict__ Vb,
    float* __restrict__ norms, float* __restrict__ ks_sum) {
  __shared__ float Asf[2][128 * 64];     // 2 x 32KB, swizzled
  __shared__ uint16_t Bs[2][256 * 64];   // 2 x 32KB, swizzled
  __shared__ float ksp[256];
  __shared__ float red[8];

  const int b0 = blockIdx.x;
  const int blk = (b0 & 7) * 384 + (b0 >> 3);  // XCD-chunked (3072 = 8*384)
  const int rt = blk / 6, rem = blk % 6;
  const int proj = rem >> 1, ct = rem & 1;
  const int row0 = rt * 128, cb = ct * 256;

  const float* A = proj ? sin_ : qin;
  const uint16_t* W = Wb + (size_t)proj * 262144;
  const float* Bi = (proj == 0) ? bq : (proj == 1) ? bk : bv;
  uint16_t* O = (proj == 0) ? Qb : (proj == 1) ? Kb : Vb;

  const int tid = threadIdx.x;
  const int lane = tid & 63;
  const int wv = tid >> 6;       // 0..7
  const int wr = wv >> 2;        // 0..1
  const int wc = wv & 3;         // 0..3
  const int l15 = lane & 15, lhi = lane >> 4;

  f32x4 acc[4][4];
#pragma unroll
  for (int m = 0; m < 4; ++m)
#pragma unroll
    for (int n = 0; n < 4; ++n) acc[m][n] = (f32x4){0.f, 0.f, 0.f, 0.f};

  // 8 DMA issues/wave into buffer `buf` for K-slice kt.
  auto stage = [&](int buf, int kt) {
    const int k0 = kt * 64;
#pragma unroll
    for (int i = 0; i < 4; ++i) {  // A: 32KB = 32 issues/block
      const int ii = wv * 4 + i;
      const int arow = ii * 4 + (lane >> 4);
      const int ac16 = (lane & 15) ^ (arow & 7);  // inverse swizzle on source
      gload_lds16(A + (size_t)(row0 + arow) * 512 + k0 + ac16 * 4,
                  &Asf[buf][ii * 256]);
    }
#pragma unroll
    for (int i = 0; i < 4; ++i) {  // B: 32KB = 32 issues/block
      const int ii = wv * 4 + i;
      const int brow = ii * 8 + (lane >> 3);
      const int bc16 = (lane & 7) ^ (brow & 7);
      gload_lds16(W + (size_t)(cb + brow) * 512 + k0 + bc16 * 8,
                  &Bs[buf][ii * 512]);
    }
  };

  stage(0, 0);
  stage(1, 1);
  __builtin_amdgcn_sched_barrier(0);

#pragma unroll
  for (int t = 0; t < 8; ++t) {
    // tile t's 8 stages landed; tile t+1's 8 (newest) stay in flight.
    if (t < 7) {
      asm volatile("s_waitcnt vmcnt(8)" ::: "memory");
    } else {
      asm volatile("s_waitcnt vmcnt(0)" ::: "memory");
    }
    __builtin_amdgcn_sched_barrier(0);
    __builtin_amdgcn_s_barrier();
    __builtin_amdgcn_sched_barrier(0);

    // Hoist ALL fragment reads of tile t (frees buf[t&1] two iters early).
    const char* ab = (const char*)Asf[t & 1];
    const char* bb = (const char*)Bs[t & 1];
    f32x4 fa[2][4][2];
    short8 bfr[2][4];
#pragma unroll
    for (int kk = 0; kk < 2; ++kk)
#pragma unroll
      for (int m = 0; m < 4; ++m) {
        const int r = wr * 64 + m * 16 + l15;
        const int base = r * 256 + kk * 128 + lhi * 32;
        const int sw = (r & 7) << 4;
        fa[kk][m][0] = *(const f32x4*)(ab + (base ^ sw));
        fa[kk][m][1] = *(const f32x4*)(ab + ((base + 16) ^ sw));
      }
#pragma unroll
    for (int kk = 0; kk < 2; ++kk)
#pragma unroll
      for (int n = 0; n < 4; ++n) {
        const int c = wc * 64 + n * 16 + l15;
        const int bo = (c * 128 + kk * 64 + lhi * 16) ^ ((c & 7) << 4);
        bfr[kk][n] = *(const short8*)(bb + bo);
      }
    asm volatile("s_waitcnt lgkmcnt(0)" ::: "memory");
    __builtin_amdgcn_sched_barrier(0);  // rule #18: fence after lgkmcnt
    __builtin_amdgcn_s_barrier();       // all waves done reading buf[t&1]
    __builtin_amdgcn_sched_barrier(0);  // pin: stage must NOT move above bar

    if (t + 2 < 8) stage(t & 1, t + 2);  // depth-2 prefetch, flies 2 kt
    __builtin_amdgcn_sched_barrier(0);   // pin: stage issued before MFMA

#pragma unroll
    for (int kk = 0; kk < 2; ++kk) {
      short8 a[4];
#pragma unroll
      for (int m = 0; m < 4; ++m) {
        uint32_t* ap = (uint32_t*)&a[m];
        ap[0] = pk2bf(fa[kk][m][0][0], fa[kk][m][0][1]);
        ap[1] = pk2bf(fa[kk][m][0][2], fa[kk][m][0][3]);
        ap[2] = pk2bf(fa[kk][m][1][0], fa[kk][m][1][1]);
        ap[3] = pk2bf(fa[kk][m][1][2], fa[kk][m][1][3]);
      }
      __builtin_amdgcn_s_setprio(1);
#pragma unroll
      for (int m = 0; m < 4; ++m)
#pragma unroll
        for (int n = 0; n < 4; ++n)
          acc[m][n] =
              __builtin_amdgcn_mfma_f32_16x16x32_bf16(a[m], bfr[kk][n], acc[m][n], 0, 0, 0);
      __builtin_amdgcn_s_setprio(0);
    }
  }

  // Epilogue: bias, bf16 store, fused reductions.
  float nrm = 0.f;
  float cs[4] = {0.f, 0.f, 0.f, 0.f};
#pragma unroll
  for (int n = 0; n < 4; ++n) {
    const int colg = cb + wc * 64 + n * 16 + l15;
    const float bias = Bi[colg];
#pragma unroll
    for (int m = 0; m < 4; ++m) {
      const int rowb = row0 + wr * 64 + m * 16 + lhi * 4;
#pragma unroll
      for (int r = 0; r < 4; ++r) {
        const float v = acc[m][n][r] + bias;
        O[(size_t)(rowb + r) * 512 + colg] = f2bf(v);
        nrm += v * v;
        cs[n] += v;
      }
    }
  }
#pragma unroll
  for (int o = 32; o >= 1; o >>= 1) nrm += __shfl_xor(nrm, o, 64);
  if (lane == 0) red[wv] = nrm;
  if (tid < 256) ksp[tid] = 0.f;
  __syncthreads();
  if (proj == 1) {
#pragma unroll
    for (int n = 0; n < 4; ++n) {
      cs[n] += __shfl_xor(cs[n], 16, 64);
      cs[n] += __shfl_xor(cs[n], 32, 64);
    }
    if (lhi == 0) {
#pragma unroll
      for (int n = 0; n < 4; ++n) atomicAdd(&ksp[wc * 64 + n * 16 + l15], cs[n]);
    }
  }
  __syncthreads();
  if (tid == 0 && proj < 2)
    atomicAdd(&norms[proj],
              red[0] + red[1] + red[2] + red[3] + red[4] + red[5] + red[6] + red[7]);
  if (proj == 1 && tid < 256) atomicAdd(&ks_sum[cb + tid], ksp[tid]);
}

// ---------------------------------------------------------------------------
// K2: kvs partials, NO atomics — 512-thread version (16 waves/CU).
// 256 blocks = 64 chunks (1024 rows) x 4 head-pairs.
// ---------------------------------------------------------------------------
__global__ __launch_bounds__(512) void k_kvs(const uint16_t* __restrict__ Kb,
                                             const uint16_t* __restrict__ Vb,
                                             float* __restrict__ part) {
  __shared__ uint16_t Ks[64 * 128];
  __shared__ uint16_t Vs[64 * 128];
  const int tid = threadIdx.x;
  const int hp = blockIdx.x & 3;
  const int chunk = blockIdx.x >> 2;
  const int tm = tid >> 4, td = tid & 15;
  const int vb = (tm >> 4) * 64;  // V col base for this k-half's head
  float acc[4][4];
#pragma unroll
  for (int a = 0; a < 4; ++a)
#pragma unroll
    for (int b = 0; b < 4; ++b) acc[a][b] = 0.f;

  for (int nb = 0; nb < 16; ++nb) {
    const int n0 = chunk * 1024 + nb * 64;
#pragma unroll
    for (int i = 0; i < 2; ++i) {
      const int id = i * 512 + tid;
      const int row = id >> 4, c8 = id & 15;
      *(uint4*)(&Ks[row * 128 + c8 * 8]) =
          *(const uint4*)(Kb + (size_t)(n0 + row) * 512 + hp * 128 + c8 * 8);
      *(uint4*)(&Vs[row * 128 + c8 * 8]) =
          *(const uint4*)(Vb + (size_t)(n0 + row) * 512 + hp * 128 + c8 * 8);
    }
    __syncthreads();
    for (int nn = 0; nn < 64; ++nn) {
      const uint2 kw = *(const uint2*)(&Ks[nn * 128 + tm * 4]);
      const uint2 vw = *(const uint2*)(&Vs[nn * 128 + vb + td * 4]);
      const float km[4] = {bflo(kw.x), bfhi(kw.x), bflo(kw.y), bfhi(kw.y)};
      const float vd[4] = {bflo(vw.x), bfhi(vw.x), bflo(vw.y), bfhi(vw.y)};
#pragma unroll
      for (int a = 0; a < 4; ++a)
#pragma unroll
        for (int b = 0; b < 4; ++b) acc[a][b] = fmaf(km[a], vd[b], acc[a][b]);
    }
    __syncthreads();
  }
  float* p = part + (size_t)chunk * 32768 + (size_t)hp * 128 * 64;
#pragma unroll
  for (int a = 0; a < 4; ++a)
#pragma unroll
    for (int b = 0; b < 4; ++b)
      p[(tm * 4 + a) * 64 + td * 4 + b] = acc[a][b];
}

// ---------------------------------------------------------------------------
// K2b: reduce partials over 64 chunks, transpose, cvt to bf16 kvsT[d][k].
// ---------------------------------------------------------------------------
__global__ __launch_bounds__(256) void k_kvsT(const float* __restrict__ part,
                                              uint16_t* __restrict__ kvsT) {
  const int id = blockIdx.x * 256 + threadIdx.x;  // 32768 = 512k x 64d
  const int k = id >> 6, d = id & 63;
  float s0 = 0.f, s1 = 0.f, s2 = 0.f, s3 = 0.f;
#pragma unroll
  for (int c = 0; c < 64; c += 4) {
    s0 += part[(size_t)(c + 0) * 32768 + id];
    s1 += part[(size_t)(c + 1) * 32768 + id];
    s2 += part[(size_t)(c + 2) * 32768 + id];
    s3 += part[(size_t)(c + 3) * 32768 + id];
  }
  kvsT[(size_t)d * 512 + k] = f2bf((s0 + s1) + (s2 + s3));
}

// ---------------------------------------------------------------------------
// K3 (fused): 128 rows/block, 512 blocks (2/CU).
// kvsT staged ONCE per block into LDS (64KB, source-swizzled DMA + XOR read).
// den prologue -> aS,bS; out = (aQ)@kvsT^T + (bV)@I_blockdiag.
// ---------------------------------------------------------------------------
__global__ __launch_bounds__(256, 2) void k_num(const uint16_t* __restrict__ Qb,
                                                const uint16_t* __restrict__ Vb,
                                                const uint16_t* __restrict__ kvsT,
                                                const float* __restrict__ ks_sum,
                                                const float* __restrict__ norms,
                                                float* __restrict__ out) {
  __shared__ uint16_t KT[64 * 512];  // 64KB, row=d (1KB), swizzled
  __shared__ float kss[512];
  __shared__ float aS[128 * 8];
  __shared__ float bS[128 * 8];
  const int tid = threadIdx.x, lane = tid & 63, wv = tid >> 6;
  const int l15 = lane & 15, lhi = lane >> 4;
  const int row0 = blockIdx.x * 128;

#pragma unroll
  for (int i = 0; i < 16; ++i) {
    const int d = wv * 16 + i;
    const int sc = lane ^ (d & 7);  // 16B chunk index within the 1KB row
    gload_lds16(kvsT + (size_t)d * 512 + sc * 8, &KT[d * 512]);
  }
  kss[tid] = ks_sum[tid];
  kss[tid + 256] = ks_sum[tid + 256];
  __syncthreads();
  const float scale = 1.0f / (sqrtf(norms[0]) * sqrtf(norms[1]));

  {  // den: thread t -> row r = t>>1, heads (t&1)*4 .. +3
    const int r = tid >> 1, h0 = (tid & 1) * 4;
#pragma unroll
    for (int hh = 0; hh < 4; ++hh) {
      const int h = h0 + hh;
      const uint16_t* q = Qb + (size_t)(row0 + r) * 512 + h * 64;
      const float* ks = &kss[h * 64];
      float dot = 0.f;
#pragma unroll
      for (int i = 0; i < 8; ++i) {
        const uint4 w = *(const uint4*)(q + i * 8);
        const uint32_t dw[4] = {w.x, w.y, w.z, w.w};
#pragma unroll
        for (int c = 0; c < 4; ++c) {
          dot = fmaf(bflo(dw[c]), ks[i * 8 + c * 2], dot);
          dot = fmaf(bfhi(dw[c]), ks[i * 8 + c * 2 + 1], dot);
        }
      }
      const float den = fmaf(scale, dot, 65536.0f);
      aS[r * 8 + h] = scale / (8.0f * den);
      bS[r * 8 + h] = 8192.0f / den;
    }
  }
  __syncthreads();

  // constant identity B-fragments: B[k][d] = (k%64 == d), k-slice (kk,lhi)
  short8 If[2][4];
#pragma unroll
  for (int kk = 0; kk < 2; ++kk)
#pragma unroll
    for (int n = 0; n < 4; ++n) {
      const int pos = n * 16 + l15 - kk * 32 - lhi * 8;  // hit if 0..7
      uint32_t* p = (uint32_t*)&If[kk][n];
#pragma unroll
      for (int jw = 0; jw < 4; ++jw)
        p[jw] = ((pos >> 1) == jw) ? ((pos & 1) ? 0x3F800000u : 0x00003F80u) : 0u;
    }

  f32x4 acc[2][4];
#pragma unroll
  for (int m = 0; m < 2; ++m)
#pragma unroll
    for (int n = 0; n < 4; ++n) acc[m][n] = (f32x4){0.f, 0.f, 0.f, 0.f};

  // Phase 1: a-scaled Q against kvsT (B-frags from LDS KT)
  for (int h = 0; h < 8; ++h) {
#pragma unroll
    for (int kk = 0; kk < 2; ++kk) {
      short8 bfr[4];
#pragma unroll
      for (int n = 0; n < 4; ++n) {
        const int d = n * 16 + l15;
        const int bo = (d * 1024 + h * 128 + kk * 64 + lhi * 16) ^ ((d & 7) << 4);
        bfr[n] = *(const short8*)((const char*)KT + bo);
      }
#pragma unroll
      for (int m = 0; m < 2; ++m) {
        const int r = wv * 32 + m * 16 + l15;
        const float sc = aS[r * 8 + h];
        const uint4 w =
            *(const uint4*)(Qb + (size_t)(row0 + r) * 512 + h * 64 + kk * 32 + lhi * 8);
        const uint32_t dw[4] = {w.x, w.y, w.z, w.w};
        short8 af;
        uint32_t* ap = (uint32_t*)&af;
#pragma unroll
        for (int c = 0; c < 4; ++c) ap[c] = pk2bf(bflo(dw[c]) * sc, bfhi(dw[c]) * sc);
#pragma unroll
        for (int n = 0; n < 4; ++n)
          acc[m][n] = __builtin_amdgcn_mfma_f32_16x16x32_bf16(af, bfr[n], acc[m][n], 0, 0, 0);
      }
    }
  }
  // Phase 2: b-scaled V against block-diag identity
  for (int h = 0; h < 8; ++h) {
#pragma unroll
    for (int kk = 0; kk < 2; ++kk) {
#pragma unroll
      for (int m = 0; m < 2; ++m) {
        const int r = wv * 32 + m * 16 + l15;
        const float sc = bS[r * 8 + h];
        const uint4 w =
            *(const uint4*)(Vb + (size_t)(row0 + r) * 512 + h * 64 + kk * 32 + lhi * 8);
        const uint32_t dw[4] = {w.x, w.y, w.z, w.w};
        short8 af;
        uint32_t* ap = (uint32_t*)&af;
#pragma unroll
        for (int c = 0; c < 4; ++c) ap[c] = pk2bf(bflo(dw[c]) * sc, bfhi(dw[c]) * sc);
#pragma unroll
        for (int n = 0; n < 4; ++n)
          acc[m][n] = __builtin_amdgcn_mfma_f32_16x16x32_bf16(af, If[kk][n], acc[m][n], 0, 0, 0);
      }
    }
  }

#pragma unroll
  for (int m = 0; m < 2; ++m)
#pragma unroll
    for (int n = 0; n < 4; ++n)
#pragma unroll
      for (int j = 0; j < 4; ++j)
        out[(size_t)(row0 + wv * 32 + m * 16 + lhi * 4 + j) * 64 + n * 16 + l15] =
            acc[m][n][j];
}

// ---------------------------------------------------------------------------
extern "C" void kernel_launch(void* const* d_in, const int* in_sizes, int n_in,
                              void* d_out, int out_size, void* d_ws, size_t ws_size,
                              hipStream_t stream) {
  const float* qin = (const float*)d_in[0];
  const float* sin_ = (const float*)d_in[1];
  const float* Wq = (const float*)d_in[2];
  const float* bq = (const float*)d_in[3];
  const float* Wk = (const float*)d_in[4];
  const float* bk = (const float*)d_in[5];
  const float* Wv = (const float*)d_in[6];
  const float* bv = (const float*)d_in[7];
  float* out = (float*)d_out;

  char* ws = (char*)d_ws;
  float* ks_sum = (float*)ws;                        // 2KB
  float* norms = (float*)(ws + 2048);                // 8B
  uint16_t* kvsT = (uint16_t*)(ws + 4096);           // 64KB
  uint16_t* Wb = (uint16_t*)(ws + 69632);            // 1.5MB
  uint16_t* Qb = (uint16_t*)(ws + (2ull << 20));                     // 64MB
  uint16_t* Kb = (uint16_t*)(ws + (2ull << 20) + 67108864ull);       // 64MB
  uint16_t* Vb = (uint16_t*)(ws + (2ull << 20) + 134217728ull);      // 64MB
  float* part = (float*)(ws + 194ull * 1048576ull);  // 8MB (64 chunks x 128KB)

  hipMemsetAsync(d_ws, 0, 2056, stream);  // ks_sum + norms only

  k_cvtw<<<dim3(768), dim3(256), 0, stream>>>(Wq, Wk, Wv, Wb);
  k_gemm_qkv<<<dim3(3072), dim3(512), 0, stream>>>(qin, sin_, Wb, bq, bk, bv,
                                                   Qb, Kb, Vb, norms, ks_sum);
  k_kvs<<<dim3(256), dim3(512), 0, stream>>>(Kb, Vb, part);
  k_kvsT<<<dim3(128), dim3(256), 0, stream>>>(part, kvsT);
  k_num<<<dim3(512), dim3(256), 0, stream>>>(Qb, Vb, kvsT, ks_sum, norms, out);
}

// Round 16
// 299.489 us; speedup vs baseline: 1.2430x; 1.2430x over previous
//
#include <hip/hip_runtime.h>
#include <stdint.h>

typedef __attribute__((ext_vector_type(8))) short short8;
typedef __attribute__((ext_vector_type(4))) float f32x4;

// HW packed f32->bf16 (RNE): dst.lo = bf16(a), dst.hi = bf16(b). gfx950.
__device__ __forceinline__ uint32_t pk2bf(float a, float b) {
  uint32_t r;
  asm("v_cvt_pk_bf16_f32 %0, %1, %2" : "=v"(r) : "v"(a), "v"(b));
  return r;
}
__device__ __forceinline__ uint16_t f2bf(float a) {
  uint32_t ua = __builtin_bit_cast(uint32_t, a);
  return (uint16_t)((ua + 0x7FFFu + ((ua >> 16) & 1u)) >> 16);
}
__device__ __forceinline__ float bflo(uint32_t w) { return __builtin_bit_cast(float, w << 16); }
__device__ __forceinline__ float bfhi(uint32_t w) { return __builtin_bit_cast(float, w & 0xFFFF0000u); }

__device__ __forceinline__ void gload_lds16(const void* g, void* l) {
  __builtin_amdgcn_global_load_lds(
      (const __attribute__((address_space(1))) uint32_t*)g,
      (__attribute__((address_space(3))) uint32_t*)l, 16, 0, 0);
}

// ---------------------------------------------------------------------------
// K0: convert Wq/Wk/Wv (512x512 f32 each) to bf16, contiguous Wb[3][262144].
// ---------------------------------------------------------------------------
__global__ __launch_bounds__(256) void k_cvtw(const float* __restrict__ Wq,
                                              const float* __restrict__ Wk,
                                              const float* __restrict__ Wv,
                                              uint16_t* __restrict__ Wb) {
  const int idx = blockIdx.x * 256 + threadIdx.x;
  const int sel = idx >> 16;
  const int e = idx & 65535;
  const float* src = (sel == 0) ? Wq : (sel == 1) ? Wk : Wv;
  const float4 v = *(const float4*)(src + (size_t)e * 4);
  uint2 p;
  p.x = pk2bf(v.x, v.y);
  p.y = pk2bf(v.z, v.w);
  *(uint2*)(Wb + (size_t)sel * 262144 + (size_t)e * 4) = p;
}

// ---------------------------------------------------------------------------
// K1: QKV projection GEMM — champion (r11/r13), verbatim. Tile 128x256,
// BK=64, 4 waves (2x2), wave tile 64x128, acc[4][8] -> 64 MFMA/kt/wave.
// A (f32) + B (bf16) via global_load_lds with source pre-swizzle.
// LDS 65KB -> 2 blocks/CU; plain 2-barrier loop. Pipelining variants
// r6/r8/r10/r12/r15 ALL measured slower — investigation closed.
// ---------------------------------------------------------------------------
__global__ __launch_bounds__(256, 2) void k_gemm_qkv(
    const float* __restrict__ qin, const float* __restrict__ sin_,
    const uint16_t* __restrict__ Wb,
    const float* __restrict__ bq, const float* __restrict__ bk,
    const float* __restrict__ bv,
    uint16_t* __restrict__ Qb, uint16_t* __restrict__ Kb, uint16_t* __restrict__ Vb,
    float* __restrict__ norms, float* __restrict__ ks_sum) {
  __shared__ float Asf[128 * 64];     // 32KB, swizzled layout
  __shared__ uint16_t Bs[256 * 64];   // 32KB, swizzled layout
  __shared__ float ksp[256];
  __shared__ float red[4];

  const int b0 = blockIdx.x;
  const int blk = (b0 & 7) * 384 + (b0 >> 3);  // XCD-chunked (3072 = 8*384)
  const int rt = blk / 6, rem = blk % 6;
  const int proj = rem >> 1, ct = rem & 1;
  const int row0 = rt * 128, cb = ct * 256;

  const float* A = proj ? sin_ : qin;
  const uint16_t* W = Wb + (size_t)proj * 262144;
  const float* Bi = (proj == 0) ? bq : (proj == 1) ? bk : bv;
  uint16_t* O = (proj == 0) ? Qb : (proj == 1) ? Kb : Vb;

  const int tid = threadIdx.x;
  const int lane = tid & 63;
  const int wv = tid >> 6;
  const int wr = wv >> 1, wc = wv & 1;
  const int l15 = lane & 15, lhi = lane >> 4;

  f32x4 acc[4][8];
#pragma unroll
  for (int m = 0; m < 4; ++m)
#pragma unroll
    for (int n = 0; n < 8; ++n) acc[m][n] = (f32x4){0.f, 0.f, 0.f, 0.f};

  for (int kt = 0; kt < 8; ++kt) {
    const int k0 = kt * 64;
#pragma unroll
    for (int i = 0; i < 8; ++i) {  // A: 8 issues/wave, 1KB each (4 rows)
      const int arow = (wv * 8 + i) * 4 + (lane >> 4);
      const int ac16 = (lane & 15) ^ (arow & 7);  // inverse swizzle on source
      gload_lds16(A + (size_t)(row0 + arow) * 512 + k0 + ac16 * 4,
                  &Asf[(wv * 8 + i) * 256]);
    }
#pragma unroll
    for (int i = 0; i < 8; ++i) {  // B: 8 issues/wave, 1KB each (8 rows)
      const int brow = (wv * 8 + i) * 8 + (lane >> 3);
      const int bc16 = (lane & 7) ^ (brow & 7);
      gload_lds16(W + (size_t)(cb + brow) * 512 + k0 + bc16 * 8,
                  &Bs[(wv * 8 + i) * 512]);
    }
    __syncthreads();
#pragma unroll
    for (int kk = 0; kk < 2; ++kk) {
      short8 a[4], b[8];
#pragma unroll
      for (int m = 0; m < 4; ++m) {
        const int r = wr * 64 + m * 16 + l15;
        const int base = r * 256 + kk * 128 + lhi * 32;
        const int sw = (r & 7) << 4;
        const f32x4 f0 = *(const f32x4*)((const char*)Asf + (base ^ sw));
        const f32x4 f1 = *(const f32x4*)((const char*)Asf + ((base + 16) ^ sw));
        uint32_t* ap = (uint32_t*)&a[m];
        ap[0] = pk2bf(f0[0], f0[1]);
        ap[1] = pk2bf(f0[2], f0[3]);
        ap[2] = pk2bf(f1[0], f1[1]);
        ap[3] = pk2bf(f1[2], f1[3]);
      }
#pragma unroll
      for (int n = 0; n < 8; ++n) {
        const int c = wc * 128 + n * 16 + l15;
        const int bo = (c * 128 + kk * 64 + lhi * 16) ^ ((c & 7) << 4);
        b[n] = *(const short8*)((const char*)Bs + bo);
      }
#pragma unroll
      for (int m = 0; m < 4; ++m)
#pragma unroll
        for (int n = 0; n < 8; ++n)
          acc[m][n] = __builtin_amdgcn_mfma_f32_16x16x32_bf16(a[m], b[n], acc[m][n], 0, 0, 0);
    }
    __syncthreads();
  }

  // Epilogue: bias, bf16 store, fused reductions.
  float nrm = 0.f;
  float cs[8];
#pragma unroll
  for (int n = 0; n < 8; ++n) cs[n] = 0.f;
#pragma unroll
  for (int n = 0; n < 8; ++n) {
    const int colg = cb + wc * 128 + n * 16 + l15;
    const float bias = Bi[colg];
#pragma unroll
    for (int m = 0; m < 4; ++m) {
      const int rowb = row0 + wr * 64 + m * 16 + lhi * 4;
#pragma unroll
      for (int r = 0; r < 4; ++r) {
        const float v = acc[m][n][r] + bias;
        O[(size_t)(rowb + r) * 512 + colg] = f2bf(v);
        nrm += v * v;
        cs[n] += v;
      }
    }
  }
#pragma unroll
  for (int o = 32; o >= 1; o >>= 1) nrm += __shfl_xor(nrm, o, 64);
  if (lane == 0) red[wv] = nrm;
  ksp[tid] = 0.f;
  __syncthreads();
  if (proj == 1) {
#pragma unroll
    for (int n = 0; n < 8; ++n) {
      cs[n] += __shfl_xor(cs[n], 16, 64);
      cs[n] += __shfl_xor(cs[n], 32, 64);
    }
    if (lhi == 0) {
#pragma unroll
      for (int n = 0; n < 8; ++n) atomicAdd(&ksp[wc * 128 + n * 16 + l15], cs[n]);
    }
  }
  __syncthreads();
  if (tid == 0 && proj < 2)
    atomicAdd(&norms[proj], red[0] + red[1] + red[2] + red[3]);
  if (proj == 1) atomicAdd(&ks_sum[cb + tid], ksp[tid]);
}

// ---------------------------------------------------------------------------
// K2: kvs partials, NO atomics — 512 threads AND 512 blocks (2 blocks/CU,
// 16 waves/CU). 128 chunks (512 rows each) x 4 head-pairs.
// ---------------------------------------------------------------------------
__global__ __launch_bounds__(512) void k_kvs(const uint16_t* __restrict__ Kb,
                                             const uint16_t* __restrict__ Vb,
                                             float* __restrict__ part) {
  __shared__ uint16_t Ks[64 * 128];
  __shared__ uint16_t Vs[64 * 128];
  const int tid = threadIdx.x;
  const int hp = blockIdx.x & 3;
  const int chunk = blockIdx.x >> 2;
  const int tm = tid >> 4, td = tid & 15;
  const int vb = (tm >> 4) * 64;  // V col base for this k-half's head
  float acc[4][4];
#pragma unroll
  for (int a = 0; a < 4; ++a)
#pragma unroll
    for (int b = 0; b < 4; ++b) acc[a][b] = 0.f;

  for (int nb = 0; nb < 8; ++nb) {
    const int n0 = chunk * 512 + nb * 64;
#pragma unroll
    for (int i = 0; i < 2; ++i) {
      const int id = i * 512 + tid;
      const int row = id >> 4, c8 = id & 15;
      *(uint4*)(&Ks[row * 128 + c8 * 8]) =
          *(const uint4*)(Kb + (size_t)(n0 + row) * 512 + hp * 128 + c8 * 8);
      *(uint4*)(&Vs[row * 128 + c8 * 8]) =
          *(const uint4*)(Vb + (size_t)(n0 + row) * 512 + hp * 128 + c8 * 8);
    }
    __syncthreads();
    for (int nn = 0; nn < 64; ++nn) {
      const uint2 kw = *(const uint2*)(&Ks[nn * 128 + tm * 4]);
      const uint2 vw = *(const uint2*)(&Vs[nn * 128 + vb + td * 4]);
      const float km[4] = {bflo(kw.x), bfhi(kw.x), bflo(kw.y), bfhi(kw.y)};
      const float vd[4] = {bflo(vw.x), bfhi(vw.x), bflo(vw.y), bfhi(vw.y)};
#pragma unroll
      for (int a = 0; a < 4; ++a)
#pragma unroll
        for (int b = 0; b < 4; ++b) acc[a][b] = fmaf(km[a], vd[b], acc[a][b]);
    }
    __syncthreads();
  }
  float* p = part + (size_t)chunk * 32768 + (size_t)hp * 128 * 64;
#pragma unroll
  for (int a = 0; a < 4; ++a)
#pragma unroll
    for (int b = 0; b < 4; ++b)
      p[(tm * 4 + a) * 64 + td * 4 + b] = acc[a][b];
}

// ---------------------------------------------------------------------------
// K2b: reduce partials over 128 chunks, transpose, cvt to bf16 kvsT[d][k].
// ---------------------------------------------------------------------------
__global__ __launch_bounds__(256) void k_kvsT(const float* __restrict__ part,
                                              uint16_t* __restrict__ kvsT) {
  const int id = blockIdx.x * 256 + threadIdx.x;  // 32768 = 512k x 64d
  const int k = id >> 6, d = id & 63;
  float s0 = 0.f, s1 = 0.f, s2 = 0.f, s3 = 0.f;
#pragma unroll
  for (int c = 0; c < 128; c += 4) {
    s0 += part[(size_t)(c + 0) * 32768 + id];
    s1 += part[(size_t)(c + 1) * 32768 + id];
    s2 += part[(size_t)(c + 2) * 32768 + id];
    s3 += part[(size_t)(c + 3) * 32768 + id];
  }
  kvsT[(size_t)d * 512 + k] = f2bf((s0 + s1) + (s2 + s3));
}

// ---------------------------------------------------------------------------
// K3 (fused): 128 rows/block, 512 blocks (2/CU).
// kvsT staged ONCE per block into LDS (64KB, source-swizzled DMA + XOR read).
// den prologue -> aS,bS; out = (aQ)@kvsT^T + (bV)@I_blockdiag.
// ---------------------------------------------------------------------------
__global__ __launch_bounds__(256, 2) void k_num(const uint16_t* __restrict__ Qb,
                                                const uint16_t* __restrict__ Vb,
                                                const uint16_t* __restrict__ kvsT,
                                                const float* __restrict__ ks_sum,
                                                const float* __restrict__ norms,
                                                float* __restrict__ out) {
  __shared__ uint16_t KT[64 * 512];  // 64KB, row=d (1KB), swizzled
  __shared__ float kss[512];
  __shared__ float aS[128 * 8];
  __shared__ float bS[128 * 8];
  const int tid = threadIdx.x, lane = tid & 63, wv = tid >> 6;
  const int l15 = lane & 15, lhi = lane >> 4;
  const int row0 = blockIdx.x * 128;

#pragma unroll
  for (int i = 0; i < 16; ++i) {
    const int d = wv * 16 + i;
    const int sc = lane ^ (d & 7);  // 16B chunk index within the 1KB row
    gload_lds16(kvsT + (size_t)d * 512 + sc * 8, &KT[d * 512]);
  }
  kss[tid] = ks_sum[tid];
  kss[tid + 256] = ks_sum[tid + 256];
  __syncthreads();
  const float scale = 1.0f / (sqrtf(norms[0]) * sqrtf(norms[1]));

  {  // den: thread t -> row r = t>>1, heads (t&1)*4 .. +3
    const int r = tid >> 1, h0 = (tid & 1) * 4;
#pragma unroll
    for (int hh = 0; hh < 4; ++hh) {
      const int h = h0 + hh;
      const uint16_t* q = Qb + (size_t)(row0 + r) * 512 + h * 64;
      const float* ks = &kss[h * 64];
      float dot = 0.f;
#pragma unroll
      for (int i = 0; i < 8; ++i) {
        const uint4 w = *(const uint4*)(q + i * 8);
        const uint32_t dw[4] = {w.x, w.y, w.z, w.w};
#pragma unroll
        for (int c = 0; c < 4; ++c) {
          dot = fmaf(bflo(dw[c]), ks[i * 8 + c * 2], dot);
          dot = fmaf(bfhi(dw[c]), ks[i * 8 + c * 2 + 1], dot);
        }
      }
      const float den = fmaf(scale, dot, 65536.0f);
      aS[r * 8 + h] = scale / (8.0f * den);
      bS[r * 8 + h] = 8192.0f / den;
    }
  }
  __syncthreads();

  // constant identity B-fragments: B[k][d] = (k%64 == d), k-slice (kk,lhi)
  short8 If[2][4];
#pragma unroll
  for (int kk = 0; kk < 2; ++kk)
#pragma unroll
    for (int n = 0; n < 4; ++n) {
      const int pos = n * 16 + l15 - kk * 32 - lhi * 8;  // hit if 0..7
      uint32_t* p = (uint32_t*)&If[kk][n];
#pragma unroll
      for (int jw = 0; jw < 4; ++jw)
        p[jw] = ((pos >> 1) == jw) ? ((pos & 1) ? 0x3F800000u : 0x00003F80u) : 0u;
    }

  f32x4 acc[2][4];
#pragma unroll
  for (int m = 0; m < 2; ++m)
#pragma unroll
    for (int n = 0; n < 4; ++n) acc[m][n] = (f32x4){0.f, 0.f, 0.f, 0.f};

  // Phase 1: a-scaled Q against kvsT (B-frags from LDS KT)
  for (int h = 0; h < 8; ++h) {
#pragma unroll
    for (int kk = 0; kk < 2; ++kk) {
      short8 bfr[4];
#pragma unroll
      for (int n = 0; n < 4; ++n) {
        const int d = n * 16 + l15;
        const int bo = (d * 1024 + h * 128 + kk * 64 + lhi * 16) ^ ((d & 7) << 4);
        bfr[n] = *(const short8*)((const char*)KT + bo);
      }
#pragma unroll
      for (int m = 0; m < 2; ++m) {
        const int r = wv * 32 + m * 16 + l15;
        const float sc = aS[r * 8 + h];
        const uint4 w =
            *(const uint4*)(Qb + (size_t)(row0 + r) * 512 + h * 64 + kk * 32 + lhi * 8);
        const uint32_t dw[4] = {w.x, w.y, w.z, w.w};
        short8 af;
        uint32_t* ap = (uint32_t*)&af;
#pragma unroll
        for (int c = 0; c < 4; ++c) ap[c] = pk2bf(bflo(dw[c]) * sc, bfhi(dw[c]) * sc);
#pragma unroll
        for (int n = 0; n < 4; ++n)
          acc[m][n] = __builtin_amdgcn_mfma_f32_16x16x32_bf16(af, bfr[n], acc[m][n], 0, 0, 0);
      }
    }
  }
  // Phase 2: b-scaled V against block-diag identity
  for (int h = 0; h < 8; ++h) {
#pragma unroll
    for (int kk = 0; kk < 2; ++kk) {
#pragma unroll
      for (int m = 0; m < 2; ++m) {
        const int r = wv * 32 + m * 16 + l15;
        const float sc = bS[r * 8 + h];
        const uint4 w =
            *(const uint4*)(Vb + (size_t)(row0 + r) * 512 + h * 64 + kk * 32 + lhi * 8);
        const uint32_t dw[4] = {w.x, w.y, w.z, w.w};
        short8 af;
        uint32_t* ap = (uint32_t*)&af;
#pragma unroll
        for (int c = 0; c < 4; ++c) ap[c] = pk2bf(bflo(dw[c]) * sc, bfhi(dw[c]) * sc);
#pragma unroll
        for (int n = 0; n < 4; ++n)
          acc[m][n] = __builtin_amdgcn_mfma_f32_16x16x32_bf16(af, If[kk][n], acc[m][n], 0, 0, 0);
      }
    }
  }

#pragma unroll
  for (int m = 0; m < 2; ++m)
#pragma unroll
    for (int n = 0; n < 4; ++n)
#pragma unroll
      for (int j = 0; j < 4; ++j)
        out[(size_t)(row0 + wv * 32 + m * 16 + lhi * 4 + j) * 64 + n * 16 + l15] =
            acc[m][n][j];
}

// ---------------------------------------------------------------------------
extern "C" void kernel_launch(void* const* d_in, const int* in_sizes, int n_in,
                              void* d_out, int out_size, void* d_ws, size_t ws_size,
                              hipStream_t stream) {
  const float* qin = (const float*)d_in[0];
  const float* sin_ = (const float*)d_in[1];
  const float* Wq = (const float*)d_in[2];
  const float* bq = (const float*)d_in[3];
  const float* Wk = (const float*)d_in[4];
  const float* bk = (const float*)d_in[5];
  const float* Wv = (const float*)d_in[6];
  const float* bv = (const float*)d_in[7];
  float* out = (float*)d_out;

  char* ws = (char*)d_ws;
  float* ks_sum = (float*)ws;                        // 2KB
  float* norms = (float*)(ws + 2048);                // 8B
  uint16_t* kvsT = (uint16_t*)(ws + 4096);           // 64KB
  uint16_t* Wb = (uint16_t*)(ws + 69632);            // 1.5MB
  uint16_t* Qb = (uint16_t*)(ws + (2ull << 20));                     // 64MB
  uint16_t* Kb = (uint16_t*)(ws + (2ull << 20) + 67108864ull);       // 64MB
  uint16_t* Vb = (uint16_t*)(ws + (2ull << 20) + 134217728ull);      // 64MB
  float* part = (float*)(ws + 194ull * 1048576ull);  // 16MB (128 chunks x 128KB)

  hipMemsetAsync(d_ws, 0, 2056, stream);  // ks_sum + norms only

  k_cvtw<<<dim3(768), dim3(256), 0, stream>>>(Wq, Wk, Wv, Wb);
  k_gemm_qkv<<<dim3(3072), dim3(256), 0, stream>>>(qin, sin_, Wb, bq, bk, bv,
                                                   Qb, Kb, Vb, norms, ks_sum);
  k_kvs<<<dim3(512), dim3(512), 0, stream>>>(Kb, Vb, part);
  k_kvsT<<<dim3(128), dim3(256), 0, stream>>>(part, kvsT);
  k_num<<<dim3(512), dim3(256), 0, stream>>>(Qb, Vb, kvsT, ks_sum, norms, out);
}

// Round 17
// 287.768 us; speedup vs baseline: 1.2936x; 1.0407x over previous
//
#include <hip/hip_runtime.h>
#include <stdint.h>

typedef __attribute__((ext_vector_type(8))) short short8;
typedef __attribute__((ext_vector_type(4))) float f32x4;

// HW packed f32->bf16 (RNE): dst.lo = bf16(a), dst.hi = bf16(b). gfx950.
__device__ __forceinline__ uint32_t pk2bf(float a, float b) {
  uint32_t r;
  asm("v_cvt_pk_bf16_f32 %0, %1, %2" : "=v"(r) : "v"(a), "v"(b));
  return r;
}
__device__ __forceinline__ uint16_t f2bf(float a) {
  uint32_t ua = __builtin_bit_cast(uint32_t, a);
  return (uint16_t)((ua + 0x7FFFu + ((ua >> 16) & 1u)) >> 16);
}
__device__ __forceinline__ float bflo(uint32_t w) { return __builtin_bit_cast(float, w << 16); }
__device__ __forceinline__ float bfhi(uint32_t w) { return __builtin_bit_cast(float, w & 0xFFFF0000u); }

__device__ __forceinline__ void gload_lds16(const void* g, void* l) {
  __builtin_amdgcn_global_load_lds(
      (const __attribute__((address_space(1))) uint32_t*)g,
      (__attribute__((address_space(3))) uint32_t*)l, 16, 0, 0);
}

// ---------------------------------------------------------------------------
// K0: convert Wq/Wk/Wv (512x512 f32 each) to bf16, contiguous Wb[3][262144].
// ---------------------------------------------------------------------------
__global__ __launch_bounds__(256) void k_cvtw(const float* __restrict__ Wq,
                                              const float* __restrict__ Wk,
                                              const float* __restrict__ Wv,
                                              uint16_t* __restrict__ Wb) {
  const int idx = blockIdx.x * 256 + threadIdx.x;
  const int sel = idx >> 16;
  const int e = idx & 65535;
  const float* src = (sel == 0) ? Wq : (sel == 1) ? Wk : Wv;
  const float4 v = *(const float4*)(src + (size_t)e * 4);
  uint2 p;
  p.x = pk2bf(v.x, v.y);
  p.y = pk2bf(v.z, v.w);
  *(uint2*)(Wb + (size_t)sel * 262144 + (size_t)e * 4) = p;
}

// ---------------------------------------------------------------------------
// K1: QKV projection GEMM — champion (r11/r13), verbatim. Tile 128x256,
// BK=64, 4 waves (2x2), wave tile 64x128, acc[4][8] -> 64 MFMA/kt/wave.
// A (f32) + B (bf16) via global_load_lds with source pre-swizzle.
// LDS 65KB -> 2 blocks/CU; plain 2-barrier loop. Pipelining variants
// r6/r8/r10/r12/r15 ALL measured slower — investigation closed.
// ---------------------------------------------------------------------------
__global__ __launch_bounds__(256, 2) void k_gemm_qkv(
    const float* __restrict__ qin, const float* __restrict__ sin_,
    const uint16_t* __restrict__ Wb,
    const float* __restrict__ bq, const float* __restrict__ bk,
    const float* __restrict__ bv,
    uint16_t* __restrict__ Qb, uint16_t* __restrict__ Kb, uint16_t* __restrict__ Vb,
    float* __restrict__ norms, float* __restrict__ ks_sum) {
  __shared__ float Asf[128 * 64];     // 32KB, swizzled layout
  __shared__ uint16_t Bs[256 * 64];   // 32KB, swizzled layout
  __shared__ float ksp[256];
  __shared__ float red[4];

  const int b0 = blockIdx.x;
  const int blk = (b0 & 7) * 384 + (b0 >> 3);  // XCD-chunked (3072 = 8*384)
  const int rt = blk / 6, rem = blk % 6;
  const int proj = rem >> 1, ct = rem & 1;
  const int row0 = rt * 128, cb = ct * 256;

  const float* A = proj ? sin_ : qin;
  const uint16_t* W = Wb + (size_t)proj * 262144;
  const float* Bi = (proj == 0) ? bq : (proj == 1) ? bk : bv;
  uint16_t* O = (proj == 0) ? Qb : (proj == 1) ? Kb : Vb;

  const int tid = threadIdx.x;
  const int lane = tid & 63;
  const int wv = tid >> 6;
  const int wr = wv >> 1, wc = wv & 1;
  const int l15 = lane & 15, lhi = lane >> 4;

  f32x4 acc[4][8];
#pragma unroll
  for (int m = 0; m < 4; ++m)
#pragma unroll
    for (int n = 0; n < 8; ++n) acc[m][n] = (f32x4){0.f, 0.f, 0.f, 0.f};

  for (int kt = 0; kt < 8; ++kt) {
    const int k0 = kt * 64;
#pragma unroll
    for (int i = 0; i < 8; ++i) {  // A: 8 issues/wave, 1KB each (4 rows)
      const int arow = (wv * 8 + i) * 4 + (lane >> 4);
      const int ac16 = (lane & 15) ^ (arow & 7);  // inverse swizzle on source
      gload_lds16(A + (size_t)(row0 + arow) * 512 + k0 + ac16 * 4,
                  &Asf[(wv * 8 + i) * 256]);
    }
#pragma unroll
    for (int i = 0; i < 8; ++i) {  // B: 8 issues/wave, 1KB each (8 rows)
      const int brow = (wv * 8 + i) * 8 + (lane >> 3);
      const int bc16 = (lane & 7) ^ (brow & 7);
      gload_lds16(W + (size_t)(cb + brow) * 512 + k0 + bc16 * 8,
                  &Bs[(wv * 8 + i) * 512]);
    }
    __syncthreads();
#pragma unroll
    for (int kk = 0; kk < 2; ++kk) {
      short8 a[4], b[8];
#pragma unroll
      for (int m = 0; m < 4; ++m) {
        const int r = wr * 64 + m * 16 + l15;
        const int base = r * 256 + kk * 128 + lhi * 32;
        const int sw = (r & 7) << 4;
        const f32x4 f0 = *(const f32x4*)((const char*)Asf + (base ^ sw));
        const f32x4 f1 = *(const f32x4*)((const char*)Asf + ((base + 16) ^ sw));
        uint32_t* ap = (uint32_t*)&a[m];
        ap[0] = pk2bf(f0[0], f0[1]);
        ap[1] = pk2bf(f0[2], f0[3]);
        ap[2] = pk2bf(f1[0], f1[1]);
        ap[3] = pk2bf(f1[2], f1[3]);
      }
#pragma unroll
      for (int n = 0; n < 8; ++n) {
        const int c = wc * 128 + n * 16 + l15;
        const int bo = (c * 128 + kk * 64 + lhi * 16) ^ ((c & 7) << 4);
        b[n] = *(const short8*)((const char*)Bs + bo);
      }
#pragma unroll
      for (int m = 0; m < 4; ++m)
#pragma unroll
        for (int n = 0; n < 8; ++n)
          acc[m][n] = __builtin_amdgcn_mfma_f32_16x16x32_bf16(a[m], b[n], acc[m][n], 0, 0, 0);
    }
    __syncthreads();
  }

  // Epilogue: bias, bf16 store, fused reductions.
  float nrm = 0.f;
  float cs[8];
#pragma unroll
  for (int n = 0; n < 8; ++n) cs[n] = 0.f;
#pragma unroll
  for (int n = 0; n < 8; ++n) {
    const int colg = cb + wc * 128 + n * 16 + l15;
    const float bias = Bi[colg];
#pragma unroll
    for (int m = 0; m < 4; ++m) {
      const int rowb = row0 + wr * 64 + m * 16 + lhi * 4;
#pragma unroll
      for (int r = 0; r < 4; ++r) {
        const float v = acc[m][n][r] + bias;
        O[(size_t)(rowb + r) * 512 + colg] = f2bf(v);
        nrm += v * v;
        cs[n] += v;
      }
    }
  }
#pragma unroll
  for (int o = 32; o >= 1; o >>= 1) nrm += __shfl_xor(nrm, o, 64);
  if (lane == 0) red[wv] = nrm;
  ksp[tid] = 0.f;
  __syncthreads();
  if (proj == 1) {
#pragma unroll
    for (int n = 0; n < 8; ++n) {
      cs[n] += __shfl_xor(cs[n], 16, 64);
      cs[n] += __shfl_xor(cs[n], 32, 64);
    }
    if (lhi == 0) {
#pragma unroll
      for (int n = 0; n < 8; ++n) atomicAdd(&ksp[wc * 128 + n * 16 + l15], cs[n]);
    }
  }
  __syncthreads();
  if (tid == 0 && proj < 2)
    atomicAdd(&norms[proj], red[0] + red[1] + red[2] + red[3]);
  if (proj == 1) atomicAdd(&ks_sum[cb + tid], ksp[tid]);
}

// ---------------------------------------------------------------------------
// K2: kvs partials, NO atomics — 512 threads AND 512 blocks (2 blocks/CU,
// 16 waves/CU). 128 chunks (512 rows each) x 4 head-pairs.
// ---------------------------------------------------------------------------
__global__ __launch_bounds__(512) void k_kvs(const uint16_t* __restrict__ Kb,
                                             const uint16_t* __restrict__ Vb,
                                             float* __restrict__ part) {
  __shared__ uint16_t Ks[64 * 128];
  __shared__ uint16_t Vs[64 * 128];
  const int tid = threadIdx.x;
  const int hp = blockIdx.x & 3;
  const int chunk = blockIdx.x >> 2;
  const int tm = tid >> 4, td = tid & 15;
  const int vb = (tm >> 4) * 64;  // V col base for this k-half's head
  float acc[4][4];
#pragma unroll
  for (int a = 0; a < 4; ++a)
#pragma unroll
    for (int b = 0; b < 4; ++b) acc[a][b] = 0.f;

  for (int nb = 0; nb < 8; ++nb) {
    const int n0 = chunk * 512 + nb * 64;
#pragma unroll
    for (int i = 0; i < 2; ++i) {
      const int id = i * 512 + tid;
      const int row = id >> 4, c8 = id & 15;
      *(uint4*)(&Ks[row * 128 + c8 * 8]) =
          *(const uint4*)(Kb + (size_t)(n0 + row) * 512 + hp * 128 + c8 * 8);
      *(uint4*)(&Vs[row * 128 + c8 * 8]) =
          *(const uint4*)(Vb + (size_t)(n0 + row) * 512 + hp * 128 + c8 * 8);
    }
    __syncthreads();
    for (int nn = 0; nn < 64; ++nn) {
      const uint2 kw = *(const uint2*)(&Ks[nn * 128 + tm * 4]);
      const uint2 vw = *(const uint2*)(&Vs[nn * 128 + vb + td * 4]);
      const float km[4] = {bflo(kw.x), bfhi(kw.x), bflo(kw.y), bfhi(kw.y)};
      const float vd[4] = {bflo(vw.x), bfhi(vw.x), bflo(vw.y), bfhi(vw.y)};
#pragma unroll
      for (int a = 0; a < 4; ++a)
#pragma unroll
        for (int b = 0; b < 4; ++b) acc[a][b] = fmaf(km[a], vd[b], acc[a][b]);
    }
    __syncthreads();
  }
  float* p = part + (size_t)chunk * 32768 + (size_t)hp * 128 * 64;
#pragma unroll
  for (int a = 0; a < 4; ++a)
#pragma unroll
    for (int b = 0; b < 4; ++b)
      p[(tm * 4 + a) * 64 + td * 4 + b] = acc[a][b];
}

// ---------------------------------------------------------------------------
// K2b: reduce partials over 128 chunks, transpose, cvt to bf16 kvsT[d][k].
// ---------------------------------------------------------------------------
__global__ __launch_bounds__(256) void k_kvsT(const float* __restrict__ part,
                                              uint16_t* __restrict__ kvsT) {
  const int id = blockIdx.x * 256 + threadIdx.x;  // 32768 = 512k x 64d
  const int k = id >> 6, d = id & 63;
  float s0 = 0.f, s1 = 0.f, s2 = 0.f, s3 = 0.f;
#pragma unroll
  for (int c = 0; c < 128; c += 4) {
    s0 += part[(size_t)(c + 0) * 32768 + id];
    s1 += part[(size_t)(c + 1) * 32768 + id];
    s2 += part[(size_t)(c + 2) * 32768 + id];
    s3 += part[(size_t)(c + 3) * 32768 + id];
  }
  kvsT[(size_t)d * 512 + k] = f2bf((s0 + s1) + (s2 + s3));
}

// ---------------------------------------------------------------------------
// K3 (fused, den-in-P1): 128 rows/block, 512 blocks (2/CU).
// kvsT staged ONCE per block into LDS (64KB, source-swizzled DMA+XOR read).
// Per head: load Q,V fragments ONCE -> den from the fragments themselves
// (8-FMA local dot vs LDS kss + shfl_xor(16/32) row-reduce) -> a,b in regs
// -> a-scaled Q x KT MFMAs + b-scaled V x I_blockdiag MFMAs.
// Saves the den pre-pass (second 64MB Qb read) and the aS/bS round-trip.
// ---------------------------------------------------------------------------
__global__ __launch_bounds__(256, 2) void k_num(const uint16_t* __restrict__ Qb,
                                                const uint16_t* __restrict__ Vb,
                                                const uint16_t* __restrict__ kvsT,
                                                const float* __restrict__ ks_sum,
                                                const float* __restrict__ norms,
                                                float* __restrict__ out) {
  __shared__ uint16_t KT[64 * 512];  // 64KB, row=d (1KB), swizzled
  __shared__ float kss[512];
  const int tid = threadIdx.x, lane = tid & 63, wv = tid >> 6;
  const int l15 = lane & 15, lhi = lane >> 4;
  const int row0 = blockIdx.x * 128;

#pragma unroll
  for (int i = 0; i < 16; ++i) {
    const int d = wv * 16 + i;
    const int sc = lane ^ (d & 7);  // 16B chunk index within the 1KB row
    gload_lds16(kvsT + (size_t)d * 512 + sc * 8, &KT[d * 512]);
  }
  kss[tid] = ks_sum[tid];
  kss[tid + 256] = ks_sum[tid + 256];
  __syncthreads();
  const float scale = 1.0f / (sqrtf(norms[0]) * sqrtf(norms[1]));

  // constant identity B-fragments: B[k][d] = (k%64 == d), k-slice (kk,lhi)
  short8 If[2][4];
#pragma unroll
  for (int kk = 0; kk < 2; ++kk)
#pragma unroll
    for (int n = 0; n < 4; ++n) {
      const int pos = n * 16 + l15 - kk * 32 - lhi * 8;  // hit if 0..7
      uint32_t* p = (uint32_t*)&If[kk][n];
#pragma unroll
      for (int jw = 0; jw < 4; ++jw)
        p[jw] = ((pos >> 1) == jw) ? ((pos & 1) ? 0x3F800000u : 0x00003F80u) : 0u;
    }

  f32x4 acc[2][4];
#pragma unroll
  for (int m = 0; m < 2; ++m)
#pragma unroll
    for (int n = 0; n < 4; ++n) acc[m][n] = (f32x4){0.f, 0.f, 0.f, 0.f};

  for (int h = 0; h < 8; ++h) {
    // --- load this head's Q and V fragments once (kept in regs) ---
    uint4 wq[2][2], wvv[2][2];
#pragma unroll
    for (int m = 0; m < 2; ++m) {
      const int r = row0 + wv * 32 + m * 16 + l15;
#pragma unroll
      for (int kk = 0; kk < 2; ++kk) {
        wq[m][kk] = *(const uint4*)(Qb + (size_t)r * 512 + h * 64 + kk * 32 + lhi * 8);
        wvv[m][kk] = *(const uint4*)(Vb + (size_t)r * 512 + h * 64 + kk * 32 + lhi * 8);
      }
    }
    // --- kss slices for this head (per kk, this lane's 8 floats) ---
    f32x4 ks0[2], ks1[2];
#pragma unroll
    for (int kk = 0; kk < 2; ++kk) {
      const float* kp = &kss[h * 64 + kk * 32 + lhi * 8];
      ks0[kk] = *(const f32x4*)kp;
      ks1[kk] = *(const f32x4*)(kp + 4);
    }
    // --- den per row-block m: local 16-FMA dot + cross-lane (lhi) reduce ---
    float rden[2];
#pragma unroll
    for (int m = 0; m < 2; ++m) {
      float d = 0.f;
#pragma unroll
      for (int kk = 0; kk < 2; ++kk) {
        const uint32_t dw[4] = {wq[m][kk].x, wq[m][kk].y, wq[m][kk].z, wq[m][kk].w};
        d = fmaf(bflo(dw[0]), ks0[kk][0], d);
        d = fmaf(bfhi(dw[0]), ks0[kk][1], d);
        d = fmaf(bflo(dw[1]), ks0[kk][2], d);
        d = fmaf(bfhi(dw[1]), ks0[kk][3], d);
        d = fmaf(bflo(dw[2]), ks1[kk][0], d);
        d = fmaf(bfhi(dw[2]), ks1[kk][1], d);
        d = fmaf(bflo(dw[3]), ks1[kk][2], d);
        d = fmaf(bfhi(dw[3]), ks1[kk][3], d);
      }
      d += __shfl_xor(d, 16, 64);
      d += __shfl_xor(d, 32, 64);
      rden[m] = 1.0f / fmaf(scale, d, 65536.0f);
    }
    // --- MFMAs: a-scaled Q x KT, b-scaled V x identity ---
#pragma unroll
    for (int kk = 0; kk < 2; ++kk) {
      short8 bfr[4];
#pragma unroll
      for (int n = 0; n < 4; ++n) {
        const int d = n * 16 + l15;
        const int bo = (d * 1024 + h * 128 + kk * 64 + lhi * 16) ^ ((d & 7) << 4);
        bfr[n] = *(const short8*)((const char*)KT + bo);
      }
#pragma unroll
      for (int m = 0; m < 2; ++m) {
        const float a_s = scale * 0.125f * rden[m];
        const float b_s = 8192.0f * rden[m];
        const uint32_t dq[4] = {wq[m][kk].x, wq[m][kk].y, wq[m][kk].z, wq[m][kk].w};
        const uint32_t dv[4] = {wvv[m][kk].x, wvv[m][kk].y, wvv[m][kk].z, wvv[m][kk].w};
        short8 af, vf;
        uint32_t* ap = (uint32_t*)&af;
        uint32_t* vp = (uint32_t*)&vf;
#pragma unroll
        for (int c = 0; c < 4; ++c) {
          ap[c] = pk2bf(bflo(dq[c]) * a_s, bfhi(dq[c]) * a_s);
          vp[c] = pk2bf(bflo(dv[c]) * b_s, bfhi(dv[c]) * b_s);
        }
#pragma unroll
        for (int n = 0; n < 4; ++n)
          acc[m][n] = __builtin_amdgcn_mfma_f32_16x16x32_bf16(af, bfr[n], acc[m][n], 0, 0, 0);
#pragma unroll
        for (int n = 0; n < 4; ++n)
          acc[m][n] = __builtin_amdgcn_mfma_f32_16x16x32_bf16(vf, If[kk][n], acc[m][n], 0, 0, 0);
      }
    }
  }

#pragma unroll
  for (int m = 0; m < 2; ++m)
#pragma unroll
    for (int n = 0; n < 4; ++n)
#pragma unroll
      for (int j = 0; j < 4; ++j)
        out[(size_t)(row0 + wv * 32 + m * 16 + lhi * 4 + j) * 64 + n * 16 + l15] =
            acc[m][n][j];
}

// ---------------------------------------------------------------------------
extern "C" void kernel_launch(void* const* d_in, const int* in_sizes, int n_in,
                              void* d_out, int out_size, void* d_ws, size_t ws_size,
                              hipStream_t stream) {
  const float* qin = (const float*)d_in[0];
  const float* sin_ = (const float*)d_in[1];
  const float* Wq = (const float*)d_in[2];
  const float* bq = (const float*)d_in[3];
  const float* Wk = (const float*)d_in[4];
  const float* bk = (const float*)d_in[5];
  const float* Wv = (const float*)d_in[6];
  const float* bv = (const float*)d_in[7];
  float* out = (float*)d_out;

  char* ws = (char*)d_ws;
  float* ks_sum = (float*)ws;                        // 2KB
  float* norms = (float*)(ws + 2048);                // 8B
  uint16_t* kvsT = (uint16_t*)(ws + 4096);           // 64KB
  uint16_t* Wb = (uint16_t*)(ws + 69632);            // 1.5MB
  uint16_t* Qb = (uint16_t*)(ws + (2ull << 20));                     // 64MB
  uint16_t* Kb = (uint16_t*)(ws + (2ull << 20) + 67108864ull);       // 64MB
  uint16_t* Vb = (uint16_t*)(ws + (2ull << 20) + 134217728ull);      // 64MB
  float* part = (float*)(ws + 194ull * 1048576ull);  // 16MB (128 chunks x 128KB)

  hipMemsetAsync(d_ws, 0, 2056, stream);  // ks_sum + norms only

  k_cvtw<<<dim3(768), dim3(256), 0, stream>>>(Wq, Wk, Wv, Wb);
  k_gemm_qkv<<<dim3(3072), dim3(256), 0, stream>>>(qin, sin_, Wb, bq, bk, bv,
                                                   Qb, Kb, Vb, norms, ks_sum);
  k_kvs<<<dim3(512), dim3(512), 0, stream>>>(Kb, Vb, part);
  k_kvsT<<<dim3(128), dim3(256), 0, stream>>>(part, kvsT);
  k_num<<<dim3(512), dim3(256), 0, stream>>>(Qb, Vb, kvsT, ks_sum, norms, out);
}